// Round 26
// baseline (83.229 us; speedup 1.0000x reference)
//
#include <hip/hip_runtime.h>

#define BATCH 4
#define CIN 256
#define FH 64
#define FW 176
#define HW (FH*FW)          // 11264
#define PHW 11748           // (FH+2)*(FW+2) padded pixels
#define C1 128
#define DBINS 64
#define NPTS 150000
#define BEVN 200
#define EPSV 1e-5f

// output offsets (floats)
#define OFF_BEV 0
#define OFF_DD  160000
#define OFF_ED  3043584
#define OFF_PTS 3088640
#define OFF_P2  3167488            // block BN partials scratch (inside PTS)

// ws byte offsets
#define WSB_H    0                 // u16[5767168]  h bf16 [b][c1][y][x]
#define WSB_WT   11534336          // u16[294912]   w1 bf16 [tap][co][cin]
#define WSB_W2B  12124160          // u16[8192]     w2 bf16 [d][c]
#define WSB_BN   12140544          // f32[256]      reduced (s,q) per ch
#define WSB_XTP  12144640          // u16[2*3007488] padded xT (batches 0,1)
#define XTP_B_ELEMS 3007488
#define WS_NEED_SPLIT 24174592ull  // xtp pair in ws; pair 2-3 borrows d_out

typedef short bfx8 __attribute__((ext_vector_type(8)));
typedef short bfx4 __attribute__((ext_vector_type(4)));
typedef float f32x4 __attribute__((ext_vector_type(4)));
typedef unsigned short u16;

__device__ __forceinline__ u16 f2bf(float f) {
  union { float f; unsigned int u; } v; v.f = f;
  unsigned int r = v.u + 0x7FFF + ((v.u >> 16) & 1);
  return (u16)(r >> 16);
}
__device__ __forceinline__ float bf2f(u16 h) {
  union { unsigned int u; float f; } v; v.u = ((unsigned int)h) << 16;
  return v.f;
}

__device__ __forceinline__ void gload_lds16(const void* g, void* l) {
  __builtin_amdgcn_global_load_lds(
      (const __attribute__((address_space(1))) unsigned int*)g,
      (__attribute__((address_space(3))) unsigned int*)l, 16, 0, 0);
}

__device__ __forceinline__ u16* xtp_base(u16* A, u16* B, int splitA, int bloc) {
  return (bloc < splitA) ? A + (size_t)bloc * XTP_B_ELEMS
                         : B + (size_t)(bloc - splitA) * XTP_B_ELEMS;
}

// ---------------- k_xt: transpose + fused init (bev/w2b/wt/borders) ---------
// grid 1024 (4 bloc x 64 rows x 4 c0-groups), 256 thr; float4 input loads
__global__ __launch_bounds__(256) void k_xt(
    const float* __restrict__ x, u16* __restrict__ xtpA,
    u16* __restrict__ xtpB, int splitA, int nbat,
    float* __restrict__ out, u16* __restrict__ w2b,
    const float* __restrict__ W2, u16* __restrict__ wt,
    const float* __restrict__ W1) {
  __shared__ u16 s_t[176 * 72];
  const int blk = blockIdx.x;
  const int t = threadIdx.x;
  const int idx = blk * 256 + t;

  // ---- fused init work (independent of transpose) ----
  if (idx < BATCH * BEVN * BEVN) out[OFF_BEV + idx] = 0.0f;
  if (idx < DBINS * C1) w2b[idx] = f2bf(W2[idx]);
  for (int i = idx; i < 9 * C1 * CIN; i += 262144) {
    int tap = i >> 15, rem = i & 32767;
    int co = rem >> 8, c = rem & 255;
    wt[i] = f2bf(W1[(co * CIN + c) * 9 + tap]);
  }
  const int nbord = nbat * 484 * 32;   // halo border bfx8 chunks
  if (idx < nbord) {
    int bloc = idx / (484 * 32);
    int r = idx - bloc * 484 * 32;
    int bpx = r >> 5, ch8 = r & 31;
    int prow, pcol;
    if (bpx < 178)      { prow = 0;  pcol = bpx; }
    else if (bpx < 356) { prow = 65; pcol = bpx - 178; }
    else { int q = bpx - 356; prow = 1 + (q >> 1); pcol = (q & 1) * 177; }
    u16* xb = xtp_base(xtpA, xtpB, splitA, bloc);
    *(bfx8*)&xb[(prow * 178 + pcol) * 256 + ch8 * 8] = (bfx8)(short)0;
  }

  // ---- transpose: one (bloc,row,c0) tile; float4 loads (44 f4 per row) ----
  const int bloc = blk >> 8;
  const int rem = blk & 255;
  const int row = rem >> 2;
  const int c0 = (rem & 3) * 64;
  #pragma unroll
  for (int i = 0; i < 11; ++i) {
    int f = i * 256 + t;
    int c = f / 44, p4 = (f - c * 44) * 4;
    const f32x4 v = *(const f32x4*)&x[((bloc * CIN + c0 + c) * FH + row) * FW + p4];
    #pragma unroll
    for (int j = 0; j < 4; ++j) s_t[(p4 + j) * 72 + c] = f2bf(v[j]);
  }
  __syncthreads();
  u16* xb = xtp_base(xtpA, xtpB, splitA, bloc);
  const int base = ((row + 1) * 178 + 1) * 256 + c0;
  #pragma unroll
  for (int i = 0; i < 6; ++i) {
    int f = i * 256 + t;
    if (f < 1408) {
      int px = f >> 3, s = f & 7;
      *(bfx8*)&xb[base + (px << 8) + s * 8] = *(const bfx8*)&s_t[px * 72 + s * 8];
    }
  }
}

// ---------------- k_conv: implicit-GEMM 3x3 conv + fused BN block partials --
// 512 thr = 8 waves (4 px-rows x 2 co-halves); tile 64px(4r x 16c) x 128co;
// BK=64; 36 steps; 2 x 24KB buffers, ONE barrier/step, issue-early + VMCNT(0).
// Epilogue: per-block per-co (s,q) partials -> part2[tile][co][2] (no atomics).
#define ABUF_E 4096          // A elems: 64px x 64cin (8 KB)
#define STEP_E 12288         // + B: 128co x 64cin (24 KB per buffer)

__global__ __launch_bounds__(512) void k_conv(
    u16* __restrict__ xtpA, u16* __restrict__ xtpB, int splitA,
    const u16* __restrict__ wt, const float* __restrict__ b1,
    u16* __restrict__ hbf, float* __restrict__ part2, int tgof, int b0) {
  __shared__ __align__(16) u16 sMem[2 * STEP_E];   // 48 KB

  const int blk = blockIdx.x;
  const int bloc = blk / 176;
  const int tile = blk % 176;           // 16 row-tiles x 11 col-tiles
  const int h0 = (tile / 11) * 4;
  const int w0 = (tile % 11) * 16;
  const int b = b0 + bloc;
  const u16* xTp = xtp_base(xtpA, xtpB, splitA, bloc);
  const int t = threadIdx.x;
  const int lane = t & 63;
  const int wv = t >> 6;                // 0..7
  const int mw = wv >> 1, nw = wv & 1;  // px row (16px), co half (64co)
  const int l15 = lane & 15, kg = lane >> 4;

  // staging: A chunk cA = t (512); B chunks cB = t, t+512 (1024)
  int gA, gB0, gB1, ldA, ldB0, ldB1;
  {
    int c = t;
    int row = c >> 3;                  // px 0..63
    int slog = (c & 7) ^ (row & 7);
    int prow = h0 + (row >> 4), pcol = w0 + (row & 15);
    gA = (prow * 178 + pcol) * 256 + slog * 8;
    ldA = c * 8;
    gB0 = row * 256 + slog * 8;        // co 0..63
    ldB0 = c * 8;
    c = t + 512; row = c >> 3;         // co 64..127
    slog = (c & 7) ^ (row & 7);
    gB1 = row * 256 + slog * 8;
    ldB1 = c * 8;
  }

  f32x4 acc[4];
  #pragma unroll
  for (int nf = 0; nf < 4; ++nf) acc[nf] = (f32x4)(0.f);

#define STAGE(S, SEL)                                                          \
  {                                                                            \
    const int tap_ = (S) >> 2, cin0_ = ((S) & 3) << 6;                         \
    const int dy_ = tap_ / 3, dx_ = tap_ - dy_ * 3;                            \
    const int ao_ = ((dy_ * 178 + dx_) << 8) + cin0_;                          \
    const int wo_ = tap_ * 32768 + cin0_;                                      \
    u16* lb_ = &sMem[(SEL) * STEP_E];                                          \
    gload_lds16(&xTp[gA + ao_], &lb_[ldA]);                                    \
    gload_lds16(&wt[gB0 + wo_], &lb_[ABUF_E + ldB0]);                          \
    gload_lds16(&wt[gB1 + wo_], &lb_[ABUF_E + ldB1]);                          \
  }

#define COMPUTE(SEL)                                                           \
  {                                                                            \
    const u16* lb_ = &sMem[(SEL) * STEP_E];                                    \
    _Pragma("unroll")                                                          \
    for (int kk = 0; kk < 2; ++kk) {                                           \
      const int ph_ = (kk * 4 + kg) ^ (l15 & 7);                               \
      bfx8 af = *(const bfx8*)&lb_[(mw * 16 + l15) * 64 + ph_ * 8];            \
      bfx8 bf[4];                                                              \
      _Pragma("unroll")                                                        \
      for (int nf = 0; nf < 4; ++nf)                                           \
        bf[nf] = *(const bfx8*)&lb_[ABUF_E + (nw * 64 + nf * 16 + l15) * 64 + ph_ * 8]; \
      _Pragma("unroll")                                                        \
      for (int nf = 0; nf < 4; ++nf)                                           \
        acc[nf] = __builtin_amdgcn_mfma_f32_16x16x32_bf16(af, bf[nf], acc[nf], 0, 0, 0); \
    }                                                                          \
  }

#define VMCNT0 asm volatile("s_waitcnt vmcnt(0)" ::: "memory")
#define BARR __builtin_amdgcn_s_barrier()
#define SCHED0 __builtin_amdgcn_sched_barrier(0)

  STAGE(0, 0);

  #pragma unroll 1
  for (int s = 0; s < 36; s += 2) {
    VMCNT0; BARR; SCHED0;
    if (s + 1 < 36) STAGE(s + 1, 1);
    COMPUTE(0);
    VMCNT0; BARR; SCHED0;
    if (s + 2 < 36) STAGE(s + 2, 0);
    COMPUTE(1);
  }

  // epilogue: h write + per-co block partials (s, q)
  {
    const int py = h0 + mw;
    float ps[4], pq[4];
    #pragma unroll
    for (int nf = 0; nf < 4; ++nf) {
      const int co = nw * 64 + nf * 16 + l15;
      const float bb = b1[co];
      bfx4 hv;
      float s = 0.f, q = 0.f;
      #pragma unroll
      for (int j = 0; j < 4; ++j) {
        float v = acc[nf][j] + bb;
        hv[j] = (short)f2bf(v);
        s += v;
        q = fmaf(v, v, q);
      }
      ps[nf] = s; pq[nf] = q;
      *(bfx4*)&hbf[((b * C1 + co) * FH + py) * FW + w0 + kg * 4] = hv;
    }
    BARR;                               // all sMem readers done; reuse as red
    float* red = (float*)sMem;
    #pragma unroll
    for (int nf = 0; nf < 4; ++nf) {
      float s = ps[nf], q = pq[nf];
      s += __shfl_xor(s, 16); s += __shfl_xor(s, 32);
      q += __shfl_xor(q, 16); q += __shfl_xor(q, 32);
      if (lane < 16) {
        int ridx = ((mw * 2 + nw) * 4 + nf) * 16 + lane;
        red[ridx] = s;
        red[512 + ridx] = q;
      }
    }
    BARR;
    if (t < 256) {
      int sq = t & 1, l = (t >> 1) & 15, nf2 = (t >> 5) & 3, nw2 = t >> 7;
      float sum = 0.f;
      #pragma unroll
      for (int m = 0; m < 4; ++m)
        sum += red[sq * 512 + ((m * 2 + nw2) * 4 + nf2) * 16 + l];
      int co = nw2 * 64 + nf2 * 16 + l;
      part2[(size_t)(tgof + blk) * 256 + co * 2 + sq] = sum;
    }
  }
#undef STAGE
#undef COMPUTE
#undef VMCNT0
#undef BARR
#undef SCHED0
}

// ---------------- k_bnred: reduce block partials -> per-ch (s,q) ------------
__global__ __launch_bounds__(256) void k_bnred(
    const float* __restrict__ part2, float* __restrict__ part, int ntiles) {
  const int ch = blockIdx.x;
  const int t = threadIdx.x;
  float s = 0.f, q = 0.f;
  for (int tile = t; tile < ntiles; tile += 256) {
    s += part2[(size_t)tile * 256 + ch * 2 + 0];
    q += part2[(size_t)tile * 256 + ch * 2 + 1];
  }
  #pragma unroll
  for (int o = 32; o; o >>= 1) {
    s += __shfl_xor(s, o);
    q += __shfl_xor(q, o);
  }
  __shared__ float rs[4], rq[4];
  int w = t >> 6;
  if ((t & 63) == 0) { rs[w] = s; rq[w] = q; }
  __syncthreads();
  if (t == 0) {
    part[ch * 2 + 0] = rs[0] + rs[1] + rs[2] + rs[3];
    part[ch * 2 + 1] = rq[0] + rq[1] + rq[2] + rq[3];
  }
}

// ---------------- k_head: BN-finalize + 1x1 conv via MFMA + softmax ---------
__global__ __launch_bounds__(256) void k_head(
    const u16* __restrict__ h, const float* __restrict__ part,
    const float* __restrict__ gamma, const float* __restrict__ beta,
    const u16* __restrict__ w2b, const float* __restrict__ b2,
    const float* __restrict__ bins, float* __restrict__ out) {
  __shared__ u16 sAct[64 * 128];       // XOR-chunk swizzled [px][c]
  __shared__ float sP[64 * 68];        // [d][px] padded
  __shared__ float sAB[256];

  const int blk = blockIdx.x;
  const int b = blk / 176;
  const int px0 = (blk % 176) * 64;
  const int t = threadIdx.x;
  const int lane = t & 63;
  const int w = t >> 6;
  const int l15 = lane & 15, kg = lane >> 4;

  if (t < 128) {
    float s = part[t * 2 + 0];
    float q = part[t * 2 + 1];
    const float inv_n = 1.0f / (float)(BATCH * HW);
    float mu = s * inv_n;
    float var = q * inv_n - mu * mu;
    float a = gamma[t] * rsqrtf(var + EPSV);
    sAB[t] = a;
    sAB[128 + t] = beta[t] - mu * a;
  }

  bfx8 bfr[4][4];
  #pragma unroll
  for (int nf = 0; nf < 4; ++nf)
    #pragma unroll
    for (int ck = 0; ck < 4; ++ck)
      bfr[nf][ck] = *(const bfx8*)&w2b[(nf * 16 + l15) * 128 + ck * 32 + kg * 8];
  float binr[4], b2r[4];
  #pragma unroll
  for (int nf = 0; nf < 4; ++nf) {
    binr[nf] = bins[nf * 16 + l15];
    b2r[nf] = b2[nf * 16 + l15];
  }
  f32x4 acc[4];
  #pragma unroll
  for (int nf = 0; nf < 4; ++nf) acc[nf] = (f32x4)(b2r[nf]);
  __syncthreads();

  #pragma unroll
  for (int i = 0; i < 4; ++i) {
    int f = t + i * 256;
    int c = f >> 3, g = f & 7;
    bfx8 v8 = *(const bfx8*)&h[(b * C1 + c) * HW + px0 + g * 8];
    float a = sAB[c], sh = sAB[128 + c];
    #pragma unroll
    for (int j = 0; j < 8; ++j) {
      int px = g * 8 + j;
      float v = fmaxf(fmaf(bf2f((u16)v8[j]), a, sh), 0.f);
      sAct[px * 128 + (((c >> 3) ^ (px & 15)) << 3) + (c & 7)] = f2bf(v);
    }
  }
  __syncthreads();

  #pragma unroll
  for (int ck = 0; ck < 4; ++ck) {
    bfx8 af = *(const bfx8*)&sAct[(w * 16 + l15) * 128 + (((ck * 4 + kg) ^ l15) << 3)];
    #pragma unroll
    for (int nf = 0; nf < 4; ++nf)
      acc[nf] = __builtin_amdgcn_mfma_f32_16x16x32_bf16(af, bfr[nf][ck], acc[nf], 0, 0, 0);
  }

  #pragma unroll
  for (int j = 0; j < 4; ++j) {
    float e[4];
    float z = 0.f, ez = 0.f;
    #pragma unroll
    for (int nf = 0; nf < 4; ++nf) {
      e[nf] = __expf(acc[nf][j]);
      z += e[nf];
      ez = fmaf(e[nf], binr[nf], ez);
    }
    #pragma unroll
    for (int o = 1; o < 16; o <<= 1) {
      z += __shfl_xor(z, o);
      ez += __shfl_xor(ez, o);
    }
    float inv = 1.0f / z;
    int px = w * 16 + kg * 4 + j;
    #pragma unroll
    for (int nf = 0; nf < 4; ++nf)
      sP[(nf * 16 + l15) * 68 + px] = e[nf] * inv;
    if (l15 == kg * 4 + j) out[OFF_ED + b * HW + px0 + px] = ez * inv;
  }
  __syncthreads();

  #pragma unroll
  for (int i = 0; i < 4; ++i) {
    int f = t + i * 256;
    int d = f >> 4, q = f & 15;
    f32x4 v;
    #pragma unroll
    for (int jj = 0; jj < 4; ++jj) v[jj] = sP[d * 68 + q * 4 + jj];
    *(f32x4*)&out[OFF_DD + (b * DBINS + d) * HW + px0 + q * 4] = v;
  }
}

// ---------------- k_points: lift + pts3d + bev splat (depth == 1/64) --------
__global__ void k_points(const float* __restrict__ uv, const float* __restrict__ kinv,
                         float* __restrict__ out) {
  int idx = blockIdx.x * 256 + threadIdx.x;
  if (idx >= BATCH * NPTS) return;
  int b = idx / NPTS;
  const float depth = 1.0f / 64.0f;
  float u = uv[idx * 2 + 0];
  float v = uv[idx * 2 + 1];
  const float* K = &kinv[b * 9];
  float p0 = (u * K[0] + v * K[1] + K[2]) * depth;
  float p1 = (u * K[3] + v * K[4] + K[5]) * depth;
  float p2 = (u * K[6] + v * K[7] + K[8]) * depth;
  out[OFF_PTS + idx * 3 + 0] = p0;
  out[OFF_PTS + idx * 3 + 1] = p1;
  out[OFF_PTS + idx * 3 + 2] = p2;
  int gx = (int)((p0 + 50.0f) * 2.0f);
  int gy = (int)((p1 + 50.0f) * 2.0f);
  gx = min(max(gx, 0), BEVN - 1);
  gy = min(max(gy, 0), BEVN - 1);
  out[OFF_BEV + (b * BEVN + gy) * BEVN + gx] = 1.0f;
}

extern "C" void kernel_launch(void* const* d_in, const int* in_sizes, int n_in,
                              void* d_out, int out_size, void* d_ws, size_t ws_size,
                              hipStream_t stream) {
  const float* x     = (const float*)d_in[0];
  const float* uv    = (const float*)d_in[1];
  const float* kinv  = (const float*)d_in[2];
  const float* w1    = (const float*)d_in[3];
  const float* b1    = (const float*)d_in[4];
  const float* gamma = (const float*)d_in[5];
  const float* beta  = (const float*)d_in[6];
  const float* w2    = (const float*)d_in[7];
  const float* b2    = (const float*)d_in[8];
  const float* bins  = (const float*)d_in[9];
  float* out = (float*)d_out;

  u16*   wsH   = (u16*)d_ws;
  u16*   wsWT  = (u16*)((char*)d_ws + WSB_WT);
  u16*   wsW2B = (u16*)((char*)d_ws + WSB_W2B);
  float* wsBN  = (float*)((char*)d_ws + WSB_BN);
  u16*   wsXTP = (u16*)((char*)d_ws + WSB_XTP);
  u16*   doXTP = (u16*)(out + OFF_DD);   // late-written output as xtp scratch
  float* part2 = out + OFF_P2;           // late-written output as BN scratch

  if (ws_size >= WS_NEED_SPLIT) {
    // xtp batches 0-1 in ws, 2-3 in d_out scratch; single conv dispatch
    k_xt<<<1024, 256, 0, stream>>>(x, wsXTP, doXTP, 2, 4, out, wsW2B, w2, wsWT, w1);
    k_conv<<<704, 512, 0, stream>>>(wsXTP, doXTP, 2, wsWT, b1, wsH, part2, 0, 0);
  } else {
    // fallback: one batch at a time, xtp in ws only
    for (int b0 = 0; b0 < BATCH; ++b0) {
      k_xt<<<256, 256, 0, stream>>>(x + (size_t)b0 * CIN * HW, wsXTP, wsXTP, 1,
                                    (b0 == 0) ? 1 : 0, out, wsW2B, w2, wsWT, w1);
      k_conv<<<176, 512, 0, stream>>>(wsXTP, wsXTP, 1, wsWT, b1, wsH,
                                      part2, b0 * 176, b0);
    }
  }
  k_bnred<<<128, 256, 0, stream>>>(part2, wsBN, 704);
  k_head<<<704, 256, 0, stream>>>(wsH, wsBN, gamma, beta, wsW2B, b2, bins, out);
  k_points<<<(BATCH * NPTS + 255) / 256, 256, 0, stream>>>(uv, kinv, out);
}

// Round 27
// 79.931 us; speedup vs baseline: 1.0413x; 1.0413x over previous
//
#include <hip/hip_runtime.h>

#define BATCH 4
#define CIN 256
#define FH 64
#define FW 176
#define HW (FH*FW)          // 11264
#define PHW 11748           // (FH+2)*(FW+2) padded pixels
#define C1 128
#define DBINS 64
#define NPTS 150000
#define BEVN 200
#define EPSV 1e-5f

// output offsets (floats)
#define OFF_BEV 0
#define OFF_DD  160000
#define OFF_ED  3043584
#define OFF_PTS 3088640

// ws byte offsets
#define WSB_H    0                 // u16[5767168]  h bf16 [b][c1][y][x]
#define WSB_WT   11534336          // u16[294912]   w1 bf16 [tap][co][cin]
#define WSB_W2B  12124160          // u16[8192]     w2 bf16 [d][c]
#define WSB_BN   12140544          // f32[1024]     per-(ch,b) partial sums
#define WSB_XTP  12144640          // u16[2*3007488] padded xT (batches 0,1)
#define XTP_B_ELEMS 3007488
#define WS_NEED_SPLIT 24174592ull  // xtp pair in ws; pair 2-3 borrows d_out

typedef short bfx8 __attribute__((ext_vector_type(8)));
typedef short bfx4 __attribute__((ext_vector_type(4)));
typedef float f32x4 __attribute__((ext_vector_type(4)));
typedef unsigned short u16;

__device__ __forceinline__ u16 f2bf(float f) {
  union { float f; unsigned int u; } v; v.f = f;
  unsigned int r = v.u + 0x7FFF + ((v.u >> 16) & 1);
  return (u16)(r >> 16);
}
__device__ __forceinline__ float bf2f(u16 h) {
  union { unsigned int u; float f; } v; v.u = ((unsigned int)h) << 16;
  return v.f;
}

__device__ __forceinline__ void gload_lds16(const void* g, void* l) {
  __builtin_amdgcn_global_load_lds(
      (const __attribute__((address_space(1))) unsigned int*)g,
      (__attribute__((address_space(3))) unsigned int*)l, 16, 0, 0);
}

__device__ __forceinline__ u16* xtp_base(u16* A, u16* B, int splitA, int bloc) {
  return (bloc < splitA) ? A + (size_t)bloc * XTP_B_ELEMS
                         : B + (size_t)(bloc - splitA) * XTP_B_ELEMS;
}

// ---------------- k_xt: transpose + fused init (bev/w2b/wt/borders) ---------
// grid 1024 (4 bloc x 64 rows x 4 c0-groups), 256 thr; float4 input loads
__global__ __launch_bounds__(256) void k_xt(
    const float* __restrict__ x, u16* __restrict__ xtpA,
    u16* __restrict__ xtpB, int splitA, int nbat,
    float* __restrict__ out, u16* __restrict__ w2b,
    const float* __restrict__ W2, u16* __restrict__ wt,
    const float* __restrict__ W1) {
  __shared__ u16 s_t[176 * 72];
  const int blk = blockIdx.x;
  const int t = threadIdx.x;
  const int idx = blk * 256 + t;

  // ---- fused init work (independent of transpose) ----
  if (idx < BATCH * BEVN * BEVN) out[OFF_BEV + idx] = 0.0f;
  if (idx < DBINS * C1) w2b[idx] = f2bf(W2[idx]);
  for (int i = idx; i < 9 * C1 * CIN; i += 262144) {
    int tap = i >> 15, rem = i & 32767;
    int co = rem >> 8, c = rem & 255;
    wt[i] = f2bf(W1[(co * CIN + c) * 9 + tap]);
  }
  const int nbord = nbat * 484 * 32;   // halo border bfx8 chunks
  if (idx < nbord) {
    int bloc = idx / (484 * 32);
    int r = idx - bloc * 484 * 32;
    int bpx = r >> 5, ch8 = r & 31;
    int prow, pcol;
    if (bpx < 178)      { prow = 0;  pcol = bpx; }
    else if (bpx < 356) { prow = 65; pcol = bpx - 178; }
    else { int q = bpx - 356; prow = 1 + (q >> 1); pcol = (q & 1) * 177; }
    u16* xb = xtp_base(xtpA, xtpB, splitA, bloc);
    *(bfx8*)&xb[(prow * 178 + pcol) * 256 + ch8 * 8] = (bfx8)(short)0;
  }

  // ---- transpose: one (bloc,row,c0) tile; float4 loads ----
  const int bloc = blk >> 8;
  const int rem = blk & 255;
  const int row = rem >> 2;
  const int c0 = (rem & 3) * 64;
  #pragma unroll
  for (int i = 0; i < 11; ++i) {
    int f = i * 256 + t;
    int c = f / 44, p4 = (f - c * 44) * 4;
    const f32x4 v = *(const f32x4*)&x[((bloc * CIN + c0 + c) * FH + row) * FW + p4];
    #pragma unroll
    for (int j = 0; j < 4; ++j) s_t[(p4 + j) * 72 + c] = f2bf(v[j]);
  }
  __syncthreads();
  u16* xb = xtp_base(xtpA, xtpB, splitA, bloc);
  const int base = ((row + 1) * 178 + 1) * 256 + c0;
  #pragma unroll
  for (int i = 0; i < 6; ++i) {
    int f = i * 256 + t;
    if (f < 1408) {
      int px = f >> 3, s = f & 7;
      *(bfx8*)&xb[base + (px << 8) + s * 8] = *(const bfx8*)&s_t[px * 72 + s * 8];
    }
  }
}

// ---------------- k_conv: implicit-GEMM 3x3 conv via bf16 MFMA --------------
// 512 thr = 8 waves (4 px-rows x 2 co-halves); tile 64px(4r x 16c) x 128co;
// BK=64; 36 steps; 2 x 24KB buffers, ONE barrier/step, issue-early + VMCNT(0).
// grid nbat*176 (704 for 4 batches). Row=128B swizzle. (converged: ~42 us)
#define ABUF_E 4096          // A elems: 64px x 64cin (8 KB)
#define STEP_E 12288         // + B: 128co x 64cin (24 KB per buffer)

__global__ __launch_bounds__(512) void k_conv(
    u16* __restrict__ xtpA, u16* __restrict__ xtpB, int splitA,
    const u16* __restrict__ wt, const float* __restrict__ b1,
    u16* __restrict__ hbf, int b0) {
  __shared__ __align__(16) u16 sMem[2 * STEP_E];   // 48 KB

  const int blk = blockIdx.x;
  const int bloc = blk / 176;
  const int tile = blk % 176;           // 16 row-tiles x 11 col-tiles
  const int h0 = (tile / 11) * 4;
  const int w0 = (tile % 11) * 16;
  const int b = b0 + bloc;
  const u16* xTp = xtp_base(xtpA, xtpB, splitA, bloc);
  const int t = threadIdx.x;
  const int lane = t & 63;
  const int wv = t >> 6;                // 0..7
  const int mw = wv >> 1, nw = wv & 1;  // px row (16px), co half (64co)
  const int l15 = lane & 15, kg = lane >> 4;

  // staging: A chunk cA = t (512); B chunks cB = t, t+512 (1024)
  int gA, gB0, gB1, ldA, ldB0, ldB1;
  {
    int c = t;
    int row = c >> 3;                  // px 0..63
    int slog = (c & 7) ^ (row & 7);
    int prow = h0 + (row >> 4), pcol = w0 + (row & 15);
    gA = (prow * 178 + pcol) * 256 + slog * 8;
    ldA = c * 8;
    gB0 = row * 256 + slog * 8;        // co 0..63
    ldB0 = c * 8;
    c = t + 512; row = c >> 3;         // co 64..127
    slog = (c & 7) ^ (row & 7);
    gB1 = row * 256 + slog * 8;
    ldB1 = c * 8;
  }

  f32x4 acc[4];
  #pragma unroll
  for (int nf = 0; nf < 4; ++nf) acc[nf] = (f32x4)(0.f);

#define STAGE(S, SEL)                                                          \
  {                                                                            \
    const int tap_ = (S) >> 2, cin0_ = ((S) & 3) << 6;                         \
    const int dy_ = tap_ / 3, dx_ = tap_ - dy_ * 3;                            \
    const int ao_ = ((dy_ * 178 + dx_) << 8) + cin0_;                          \
    const int wo_ = tap_ * 32768 + cin0_;                                      \
    u16* lb_ = &sMem[(SEL) * STEP_E];                                          \
    gload_lds16(&xTp[gA + ao_], &lb_[ldA]);                                    \
    gload_lds16(&wt[gB0 + wo_], &lb_[ABUF_E + ldB0]);                          \
    gload_lds16(&wt[gB1 + wo_], &lb_[ABUF_E + ldB1]);                          \
  }

#define COMPUTE(SEL)                                                           \
  {                                                                            \
    const u16* lb_ = &sMem[(SEL) * STEP_E];                                    \
    _Pragma("unroll")                                                          \
    for (int kk = 0; kk < 2; ++kk) {                                           \
      const int ph_ = (kk * 4 + kg) ^ (l15 & 7);                               \
      bfx8 af = *(const bfx8*)&lb_[(mw * 16 + l15) * 64 + ph_ * 8];            \
      bfx8 bf[4];                                                              \
      _Pragma("unroll")                                                        \
      for (int nf = 0; nf < 4; ++nf)                                           \
        bf[nf] = *(const bfx8*)&lb_[ABUF_E + (nw * 64 + nf * 16 + l15) * 64 + ph_ * 8]; \
      _Pragma("unroll")                                                        \
      for (int nf = 0; nf < 4; ++nf)                                           \
        acc[nf] = __builtin_amdgcn_mfma_f32_16x16x32_bf16(af, bf[nf], acc[nf], 0, 0, 0); \
    }                                                                          \
  }

#define VMCNT0 asm volatile("s_waitcnt vmcnt(0)" ::: "memory")
#define BARR __builtin_amdgcn_s_barrier()
#define SCHED0 __builtin_amdgcn_sched_barrier(0)

  STAGE(0, 0);

  #pragma unroll 1
  for (int s = 0; s < 36; s += 2) {
    VMCNT0; BARR; SCHED0;
    if (s + 1 < 36) STAGE(s + 1, 1);
    COMPUTE(0);
    VMCNT0; BARR; SCHED0;
    if (s + 2 < 36) STAGE(s + 2, 0);
    COMPUTE(1);
  }

  // epilogue: py = h0 + mw; co = nw*64 + nf*16 + l15; x = w0 + kg*4+j
  {
    const int py = h0 + mw;
    #pragma unroll
    for (int nf = 0; nf < 4; ++nf) {
      const int co = nw * 64 + nf * 16 + l15;
      const float bb = b1[co];
      bfx4 hv;
      #pragma unroll
      for (int j = 0; j < 4; ++j) hv[j] = (short)f2bf(acc[nf][j] + bb);
      *(bfx4*)&hbf[((b * C1 + co) * FH + py) * FW + w0 + kg * 4] = hv;
    }
  }
#undef STAGE
#undef COMPUTE
#undef VMCNT0
#undef BARR
#undef SCHED0
}

// ---------------- k_bnsum: per-(ch,b) partial sum/sumsq ---------------------
__global__ __launch_bounds__(256) void k_bnsum(
    const u16* __restrict__ h, float* __restrict__ part) {
  const int ch = blockIdx.x >> 2, b = blockIdx.x & 3;
  const int t = threadIdx.x;
  float s = 0.f, q = 0.f;
  const bfx8* p = (const bfx8*)&h[(b * C1 + ch) * HW];
  for (int i = t; i < HW / 8; i += 256) {
    bfx8 v8 = p[i];
    #pragma unroll
    for (int j = 0; j < 8; ++j) {
      float v = bf2f((u16)v8[j]);
      s += v;
      q = fmaf(v, v, q);
    }
  }
  #pragma unroll
  for (int o = 32; o; o >>= 1) {
    s += __shfl_xor(s, o);
    q += __shfl_xor(q, o);
  }
  __shared__ float rs[4], rq[4];
  int w = t >> 6;
  if ((t & 63) == 0) { rs[w] = s; rq[w] = q; }
  __syncthreads();
  if (t == 0) {
    part[ch * 8 + b * 2 + 0] = rs[0] + rs[1] + rs[2] + rs[3];
    part[ch * 8 + b * 2 + 1] = rq[0] + rq[1] + rq[2] + rq[3];
  }
}

// ---------------- k_head: BN-finalize + 1x1 conv MFMA + softmax + points ----
__global__ __launch_bounds__(256) void k_head(
    const u16* __restrict__ h, const float* __restrict__ part,
    const float* __restrict__ gamma, const float* __restrict__ beta,
    const u16* __restrict__ w2b, const float* __restrict__ b2,
    const float* __restrict__ bins, const float* __restrict__ uv,
    const float* __restrict__ kinv, float* __restrict__ out) {
  __shared__ u16 sAct[64 * 128];       // XOR-chunk swizzled [px][c]
  __shared__ float sP[64 * 68];        // [d][px] padded
  __shared__ float sAB[256];

  const int blk = blockIdx.x;
  const int b = blk / 176;
  const int px0 = (blk % 176) * 64;
  const int t = threadIdx.x;
  const int lane = t & 63;
  const int w = t >> 6;
  const int l15 = lane & 15, kg = lane >> 4;

  if (t < 128) {
    float s = 0.f, q = 0.f;
    #pragma unroll
    for (int bb = 0; bb < 4; ++bb) {
      s += part[t * 8 + bb * 2 + 0];
      q += part[t * 8 + bb * 2 + 1];
    }
    const float inv_n = 1.0f / (float)(BATCH * HW);
    float mu = s * inv_n;
    float var = q * inv_n - mu * mu;
    float a = gamma[t] * rsqrtf(var + EPSV);
    sAB[t] = a;
    sAB[128 + t] = beta[t] - mu * a;
  }

  bfx8 bfr[4][4];
  #pragma unroll
  for (int nf = 0; nf < 4; ++nf)
    #pragma unroll
    for (int ck = 0; ck < 4; ++ck)
      bfr[nf][ck] = *(const bfx8*)&w2b[(nf * 16 + l15) * 128 + ck * 32 + kg * 8];
  float binr[4], b2r[4];
  #pragma unroll
  for (int nf = 0; nf < 4; ++nf) {
    binr[nf] = bins[nf * 16 + l15];
    b2r[nf] = b2[nf * 16 + l15];
  }
  f32x4 acc[4];
  #pragma unroll
  for (int nf = 0; nf < 4; ++nf) acc[nf] = (f32x4)(b2r[nf]);
  __syncthreads();

  #pragma unroll
  for (int i = 0; i < 4; ++i) {
    int f = t + i * 256;
    int c = f >> 3, g = f & 7;
    bfx8 v8 = *(const bfx8*)&h[(b * C1 + c) * HW + px0 + g * 8];
    float a = sAB[c], sh = sAB[128 + c];
    #pragma unroll
    for (int j = 0; j < 8; ++j) {
      int px = g * 8 + j;
      float v = fmaxf(fmaf(bf2f((u16)v8[j]), a, sh), 0.f);
      sAct[px * 128 + (((c >> 3) ^ (px & 15)) << 3) + (c & 7)] = f2bf(v);
    }
  }
  __syncthreads();

  #pragma unroll
  for (int ck = 0; ck < 4; ++ck) {
    bfx8 af = *(const bfx8*)&sAct[(w * 16 + l15) * 128 + (((ck * 4 + kg) ^ l15) << 3)];
    #pragma unroll
    for (int nf = 0; nf < 4; ++nf)
      acc[nf] = __builtin_amdgcn_mfma_f32_16x16x32_bf16(af, bfr[nf][ck], acc[nf], 0, 0, 0);
  }

  #pragma unroll
  for (int j = 0; j < 4; ++j) {
    float e[4];
    float z = 0.f, ez = 0.f;
    #pragma unroll
    for (int nf = 0; nf < 4; ++nf) {
      e[nf] = __expf(acc[nf][j]);
      z += e[nf];
      ez = fmaf(e[nf], binr[nf], ez);
    }
    #pragma unroll
    for (int o = 1; o < 16; o <<= 1) {
      z += __shfl_xor(z, o);
      ez += __shfl_xor(ez, o);
    }
    float inv = 1.0f / z;
    int px = w * 16 + kg * 4 + j;
    #pragma unroll
    for (int nf = 0; nf < 4; ++nf)
      sP[(nf * 16 + l15) * 68 + px] = e[nf] * inv;
    if (l15 == kg * 4 + j) out[OFF_ED + b * HW + px0 + px] = ez * inv;
  }
  __syncthreads();

  #pragma unroll
  for (int i = 0; i < 4; ++i) {
    int f = t + i * 256;
    int d = f >> 4, q = f & 15;
    f32x4 v;
    #pragma unroll
    for (int jj = 0; jj < 4; ++jj) v[jj] = sP[d * 68 + q * 4 + jj];
    *(f32x4*)&out[OFF_DD + (b * DBINS + d) * HW + px0 + q * 4] = v;
  }

  // ---- fused points: lift + pts3d + bev splat (depth == 1/64 analytically) -
  const int gtid = blk * 256 + t;
  for (int idx = gtid; idx < BATCH * NPTS; idx += 704 * 256) {
    int pb = idx / NPTS;
    const float depth = 1.0f / 64.0f;
    float u = uv[idx * 2 + 0];
    float v = uv[idx * 2 + 1];
    const float* K = &kinv[pb * 9];
    float p0 = (u * K[0] + v * K[1] + K[2]) * depth;
    float p1 = (u * K[3] + v * K[4] + K[5]) * depth;
    float p2 = (u * K[6] + v * K[7] + K[8]) * depth;
    out[OFF_PTS + idx * 3 + 0] = p0;
    out[OFF_PTS + idx * 3 + 1] = p1;
    out[OFF_PTS + idx * 3 + 2] = p2;
    int gx = (int)((p0 + 50.0f) * 2.0f);
    int gy = (int)((p1 + 50.0f) * 2.0f);
    gx = min(max(gx, 0), BEVN - 1);
    gy = min(max(gy, 0), BEVN - 1);
    out[OFF_BEV + (pb * BEVN + gy) * BEVN + gx] = 1.0f;
  }
}

extern "C" void kernel_launch(void* const* d_in, const int* in_sizes, int n_in,
                              void* d_out, int out_size, void* d_ws, size_t ws_size,
                              hipStream_t stream) {
  const float* x     = (const float*)d_in[0];
  const float* uv    = (const float*)d_in[1];
  const float* kinv  = (const float*)d_in[2];
  const float* w1    = (const float*)d_in[3];
  const float* b1    = (const float*)d_in[4];
  const float* gamma = (const float*)d_in[5];
  const float* beta  = (const float*)d_in[6];
  const float* w2    = (const float*)d_in[7];
  const float* b2    = (const float*)d_in[8];
  const float* bins  = (const float*)d_in[9];
  float* out = (float*)d_out;

  u16*   wsH   = (u16*)d_ws;
  u16*   wsWT  = (u16*)((char*)d_ws + WSB_WT);
  u16*   wsW2B = (u16*)((char*)d_ws + WSB_W2B);
  float* wsBN  = (float*)((char*)d_ws + WSB_BN);
  u16*   wsXTP = (u16*)((char*)d_ws + WSB_XTP);
  u16*   doXTP = (u16*)(out + OFF_DD);   // late-written output as xtp scratch

  if (ws_size >= WS_NEED_SPLIT) {
    // xtp batches 0-1 in ws, 2-3 in d_out scratch; single conv dispatch
    k_xt<<<1024, 256, 0, stream>>>(x, wsXTP, doXTP, 2, 4, out, wsW2B, w2, wsWT, w1);
    k_conv<<<704, 512, 0, stream>>>(wsXTP, doXTP, 2, wsWT, b1, wsH, 0);
  } else {
    // fallback: one batch at a time, xtp in ws only
    for (int b0 = 0; b0 < BATCH; ++b0) {
      k_xt<<<256, 256, 0, stream>>>(x + (size_t)b0 * CIN * HW, wsXTP, wsXTP, 1,
                                    (b0 == 0) ? 1 : 0, out, wsW2B, w2, wsWT, w1);
      k_conv<<<176, 512, 0, stream>>>(wsXTP, wsXTP, 1, wsWT, b1, wsH, b0);
    }
  }
  k_bnsum<<<512, 256, 0, stream>>>(wsH, wsBN);
  k_head<<<704, 256, 0, stream>>>(wsH, wsBN, gamma, beta, wsW2B, b2, bins,
                                  uv, kinv, out);
}